// Round 3
// baseline (263.312 us; speedup 1.0000x reference)
//
#include <hip/hip_runtime.h>

typedef __attribute__((ext_vector_type(8))) __bf16 bf16x8;
typedef __attribute__((ext_vector_type(2))) __bf16 bf16x2;
typedef __attribute__((ext_vector_type(4))) float f32x4;

#define LOG2E 1.44269504088896f
#define KSWZ(t) (((t) & 7) << 4)
#define VSWZ(d) ((((d) & 7) ^ (((d) >> 3) & 7)) << 4)

// 28 instances of dilated causal attention, each L=2048, d=64.
// q/k/v: (1, 8192, 12, 64) fp32 -> elem = tok*768 + head*64 + d.
// Block = 512 threads (8 waves): waves 0-3 = KV-group 0 (even kt),
// waves 4-7 = KV-group 1 (odd kt), same 64 q-rows; LDS merge at end.
// Double-buffered reg-staged prefetch, 1 barrier per KV tile.
// LDS pool (80 KB): grp*32K + buf*16K -> [K 8K | V^T 8K]; P bridge at 64K.

__global__ __launch_bounds__(512, 4)
void dilattn_kernel(const float* __restrict__ Qg, const float* __restrict__ Kg,
                    const float* __restrict__ Vg, float* __restrict__ Og,
                    const int* __restrict__ causal_p)
{
    extern __shared__ char pool[];

    const int bid  = blockIdx.x;
    const int inst = bid >> 5;                 // inst-major: L2 locality
    const int qt   = 31 - (bid & 31);          // heavy tiles first within inst
    int head, sstart, r, off;
    if (inst < 16)      { head = inst & 3;          sstart = (inst >> 2) * 2048; r = 1; off = 0; }
    else if (inst < 24) { int j = inst - 16; head = 4 + (j & 3); sstart = (j >> 2) * 4096; r = 2; off = 1; }
    else                { head = 8 + (inst - 24);   sstart = 0;                  r = 4; off = 2; }

    const int causal = *causal_p;
    const int tid  = threadIdx.x;
    const int lane = tid & 63;
    const int wave = tid >> 6;                 // 0..7
    const int grp  = wave >> 2;                // 0: even kt, 1: odd kt
    const int wv   = wave & 3;                 // q-row sub-tile
    const int l15  = lane & 15;
    const int lhi  = lane >> 4;
    const int t2   = tid & 255;                // thread id within group

    char* Pb = pool + 65536 + wave * 2048;     // 2 KB per-wave P bridge

    // ---- Q fragments (scale * log2e folded in) ----
    const int qrow_base = qt * 64 + wv * 16;
    const float qscale = 0.125f * LOG2E;
    bf16x8 qfrag[2];
    {
        int qr = qrow_base + l15;
        long qtok = sstart + off + (long)r * qr;
        const float* qp = Qg + qtok * 768 + head * 64 + lhi * 8;
#pragma unroll
        for (int dc = 0; dc < 2; dc++) {
            f32x4 a = *(const f32x4*)(qp + dc * 32);
            f32x4 b = *(const f32x4*)(qp + dc * 32 + 4);
#pragma unroll
            for (int j = 0; j < 4; j++) {
                qfrag[dc][j]     = (__bf16)(a[j] * qscale);
                qfrag[dc][4 + j] = (__bf16)(b[j] * qscale);
            }
        }
    }

    f32x4 acc[4] = {};
    float m_run[4] = {-INFINITY, -INFINITY, -INFINITY, -INFINITY};
    float l_run[4] = {0.f, 0.f, 0.f, 0.f};

    const int nkt = causal ? (qt + 1) : 32;
    const int nIter = (nkt + 1) >> 1;

    // staging registers (tile in flight)
    f32x4 rk0, rk1, rk2, rk3, rv0, rv1, rv2, rv3;
    const int tokK = t2 >> 2, q4 = t2 & 3;     // K: (token, d-quarter)
    const int tokP = t2 >> 3, d8 = (t2 & 7) * 8; // V: (token-pair, 8 d)

    auto load_tile = [&](int kt) {
        long kt64 = sstart + off + (long)r * (kt * 64);
        const float* kp = Kg + (kt64 + (long)r * tokK) * 768 + head * 64 + q4 * 16;
        rk0 = *(const f32x4*)(kp);
        rk1 = *(const f32x4*)(kp + 4);
        rk2 = *(const f32x4*)(kp + 8);
        rk3 = *(const f32x4*)(kp + 12);
        const float* vp0 = Vg + (kt64 + (long)r * 2 * tokP) * 768 + head * 64 + d8;
        const float* vp1 = vp0 + (long)r * 768;
        rv0 = *(const f32x4*)(vp0);
        rv1 = *(const f32x4*)(vp0 + 4);
        rv2 = *(const f32x4*)(vp1);
        rv3 = *(const f32x4*)(vp1 + 4);
    };

    // prologue: loads for this group's first tile
    if (grp < nkt) load_tile(grp);

    for (int i = 0; i < nIter; i++) {
        const int kt = 2 * i + grp;
        const bool act = kt < nkt;
        char* Kb = pool + grp * 32768 + (i & 1) * 16384;
        char* Vb = Kb + 8192;

        if (act) {
            // ---- convert staged regs -> LDS (bf16, swizzled) ----
            bf16x8 w0, w1;
#pragma unroll
            for (int j = 0; j < 4; j++) {
                w0[j] = (__bf16)rk0[j]; w0[4 + j] = (__bf16)rk1[j];
                w1[j] = (__bf16)rk2[j]; w1[4 + j] = (__bf16)rk3[j];
            }
            int kbase = tokK * 128 + q4 * 32;
            *(bf16x8*)(Kb + ((kbase)      ^ KSWZ(tokK))) = w0;
            *(bf16x8*)(Kb + ((kbase + 16) ^ KSWZ(tokK))) = w1;
#pragma unroll
            for (int j = 0; j < 4; j++) {
                int d = d8 + j;
                bf16x2 w; w[0] = (__bf16)rv0[j]; w[1] = (__bf16)rv2[j];
                *(bf16x2*)(Vb + ((d * 128 + tokP * 4) ^ VSWZ(d))) = w;
                int d2 = d8 + 4 + j;
                bf16x2 w2; w2[0] = (__bf16)rv1[j]; w2[1] = (__bf16)rv3[j];
                *(bf16x2*)(Vb + ((d2 * 128 + tokP * 4) ^ VSWZ(d2))) = w2;
            }
        }
        __syncthreads();                       // tile staged; prev readers done

        // ---- prefetch next tile into regs (overlaps compute below) ----
        if (kt + 2 < nkt) load_tile(kt + 2);

        if (act) {
            // ---- S = Q K^T ----
            f32x4 s[4];
#pragma unroll
            for (int nt = 0; nt < 4; nt++) {
                f32x4 c = {};
#pragma unroll
                for (int dc = 0; dc < 2; dc++) {
                    int krow = nt * 16 + l15;
                    const bf16x8 kf = *(const bf16x8*)(Kb +
                        ((krow * 128 + dc * 64 + lhi * 16) ^ KSWZ(krow)));
                    c = __builtin_amdgcn_mfma_f32_16x16x32_bf16(qfrag[dc], kf, c, 0, 0, 0);
                }
                s[nt] = c;
            }
            // ---- causal mask (diagonal tile only) ----
            if (causal && kt == qt) {
#pragma unroll
                for (int nt = 0; nt < 4; nt++) {
                    int kc = kt * 64 + nt * 16 + l15;
#pragma unroll
                    for (int reg = 0; reg < 4; reg++) {
                        int qr = qrow_base + lhi * 4 + reg;
                        if (kc > qr) s[nt][reg] = -INFINITY;
                    }
                }
            }
            // ---- online softmax ----
            float sc_reg[4];
#pragma unroll
            for (int reg = 0; reg < 4; reg++) {
                float mt = fmaxf(fmaxf(s[0][reg], s[1][reg]), fmaxf(s[2][reg], s[3][reg]));
#pragma unroll
                for (int x = 1; x < 16; x <<= 1) mt = fmaxf(mt, __shfl_xor(mt, x));
                float mn = fmaxf(m_run[reg], mt);
                float sc = exp2f(m_run[reg] - mn);
                float ps = 0.f;
#pragma unroll
                for (int nt = 0; nt < 4; nt++) {
                    float p = exp2f(s[nt][reg] - mn);
                    s[nt][reg] = p;
                    ps += p;
                }
#pragma unroll
                for (int x = 1; x < 16; x <<= 1) ps += __shfl_xor(ps, x);
                l_run[reg] = l_run[reg] * sc + ps;
                m_run[reg] = mn;
                sc_reg[reg] = sc;
            }
#pragma unroll
            for (int dt = 0; dt < 4; dt++)
#pragma unroll
                for (int reg = 0; reg < 4; reg++) acc[dt][reg] *= sc_reg[reg];
            // ---- P -> wave-private LDS bridge ----
#pragma unroll
            for (int reg = 0; reg < 4; reg++) {
                int row = lhi * 4 + reg;
                int rs = (row & 7) << 4;
#pragma unroll
                for (int nt = 0; nt < 4; nt++) {
                    int colb = (nt * 16 + l15) * 2;
                    *(__bf16*)(Pb + ((row * 128 + colb) ^ rs)) = (__bf16)s[nt][reg];
                }
            }
            // ---- O += P V ----
#pragma unroll
            for (int kc = 0; kc < 2; kc++) {
                const bf16x8 pf = *(const bf16x8*)(Pb +
                    ((l15 * 128 + kc * 64 + lhi * 16) ^ ((l15 & 7) << 4)));
#pragma unroll
                for (int dt = 0; dt < 4; dt++) {
                    int drow = dt * 16 + l15;
                    const bf16x8 vf = *(const bf16x8*)(Vb +
                        ((drow * 128 + kc * 64 + lhi * 16) ^ VSWZ(drow)));
                    acc[dt] = __builtin_amdgcn_mfma_f32_16x16x32_bf16(pf, vf, acc[dt], 0, 0, 0);
                }
            }
        }
    }

    // ---- merge group 1 partials into group 0 ----
    __syncthreads();                           // all compute done; buffers free
    if (wave >= 4) {
        float* ab = (float*)(pool + wv * 4096);
#pragma unroll
        for (int dt = 0; dt < 4; dt++)
            *(f32x4*)(ab + lane * 16 + dt * 4) = acc[dt];
        float* ml = (float*)(pool + 65536 + wave * 2048);
        if (l15 == 0) {
#pragma unroll
            for (int reg = 0; reg < 4; reg++) {
                int row = lhi * 4 + reg;
                ml[row * 2]     = m_run[reg];
                ml[row * 2 + 1] = l_run[reg];
            }
        }
    }
    __syncthreads();
    if (wave < 4) {
        float* ab = (float*)(pool + wv * 4096);
        float* ml = (float*)(pool + 65536 + (4 + wv) * 2048);
#pragma unroll
        for (int reg = 0; reg < 4; reg++) {
            int row = lhi * 4 + reg;
            float m1 = ml[row * 2];
            float l1 = ml[row * 2 + 1];
            float m0 = m_run[reg], l0 = l_run[reg];
            float m  = fmaxf(m0, m1);
            float sc0 = exp2f(m0 - m);
            float sc1 = exp2f(m1 - m);
            l_run[reg] = l0 * sc0 + l1 * sc1;
#pragma unroll
            for (int dt = 0; dt < 4; dt++)
                acc[dt][reg] = acc[dt][reg] * sc0 + ab[lane * 16 + dt * 4 + reg] * sc1;
        }
        // ---- epilogue: normalize + scatter ----
#pragma unroll
        for (int reg = 0; reg < 4; reg++) {
            float inv = 1.0f / l_run[reg];
            int qr = qrow_base + lhi * 4 + reg;
            long tok = sstart + off + (long)r * qr;
            float* op = Og + tok * 768 + head * 64 + l15;
#pragma unroll
            for (int dt = 0; dt < 4; dt++) op[dt * 16] = acc[dt][reg] * inv;
        }
    }
}

extern "C" void kernel_launch(void* const* d_in, const int* in_sizes, int n_in,
                              void* d_out, int out_size, void* d_ws, size_t ws_size,
                              hipStream_t stream)
{
    const float* q = (const float*)d_in[0];
    const float* k = (const float*)d_in[1];
    const float* v = (const float*)d_in[2];
    const int* causal = (const int*)d_in[3];
    float* out = (float*)d_out;

    hipMemsetAsync(d_out, 0, (size_t)out_size * sizeof(float), stream);

    dilattn_kernel<<<dim3(28 * 32), dim3(512), 81920, stream>>>(q, k, v, out, causal);
}

// Round 4
// 100.051 us; speedup vs baseline: 2.6318x; 2.6318x over previous
//
#include <hip/hip_runtime.h>

typedef __attribute__((ext_vector_type(8))) __bf16 bf16x8;
typedef __attribute__((ext_vector_type(2))) __bf16 bf16x2;
typedef __attribute__((ext_vector_type(4))) float f32x4;

#define LOG2E 1.44269504088896f
#define KSWZ(t) (((t) & 7) << 4)
#define VSWZ(d) ((((d) & 7) ^ (((d) >> 3) & 7)) << 4)

// 28 instances of dilated causal attention, each L=2048, d=64.
// q/k/v: (1, 8192, 12, 64) fp32 -> elem = tok*768 + head*64 + d.
//
// Flash-decode decomposition: each (inst, qt) splits into ceil((qt+1)/8)
// chunks of <=8 KV tiles. 80 units per instance -> 2240 balanced blocks.
// qt<8 (single chunk): write output directly. qt>=8: write unnormalized
// partial (O,m,l) to ws slot; merge kernel combines 2..4 chunks.
// ws slot layout: 4224 floats = O[64][64] + m[64] + l[64]; slot = inst*72+(u-8).

__device__ __forceinline__ void inst_decode(int inst, int& head, int& sstart,
                                            int& r, int& off)
{
    if (inst < 16)      { head = inst & 3;          sstart = (inst >> 2) * 2048; r = 1; off = 0; }
    else if (inst < 24) { int j = inst - 16; head = 4 + (j & 3); sstart = (j >> 2) * 4096; r = 2; off = 1; }
    else                { head = 8 + (inst - 24);   sstart = 0;                  r = 4; off = 2; }
}

__global__ __launch_bounds__(256)
void dilattn_partial(const float* __restrict__ Qg, const float* __restrict__ Kg,
                     const float* __restrict__ Vg, float* __restrict__ Og,
                     float* __restrict__ ws, const int* __restrict__ causal_p)
{
    const int bid  = blockIdx.x;
    const int inst = bid / 80;
    const int u    = 79 - (bid % 80);          // heavy chunks first
    int qt, c;
    if (u < 8) { qt = u; c = 0; }
    else {
        int v = u - 8;
        if (v < 16)      { qt = 8  + (v >> 1); c = v & 1; }
        else if (v < 40) { int t = v - 16; int q3 = t / 3; qt = 16 + q3; c = t - 3 * q3; }
        else             { int t = v - 40; qt = 24 + (t >> 2); c = t & 3; }
    }
    int head, sstart, r, off;
    inst_decode(inst, head, sstart, r, off);

    const int causal = *causal_p;
    int kt_begin, kt_end;
    bool direct;
    if (causal) {
        int nkt = qt + 1;
        kt_begin = c * 8;
        kt_end   = (kt_begin + 8 < nkt) ? kt_begin + 8 : nkt;
        direct   = (qt < 8);
    } else {
        if (c) return;                         // non-causal: single full pass
        kt_begin = 0; kt_end = 32; direct = true;
    }

    const int tid  = threadIdx.x;
    const int lane = tid & 63;
    const int wave = tid >> 6;                 // 0..3
    const int l15  = lane & 15;
    const int lhi  = lane >> 4;

    __shared__ __bf16 K_lds[64 * 64];
    __shared__ __bf16 Vt_lds[64 * 64];
    __shared__ __bf16 P_lds[4][16 * 64];

    // ---- Q fragments (scale * log2e folded in) ----
    const int qrow_base = qt * 64 + wave * 16;
    const float qscale = 0.125f * LOG2E;
    bf16x8 qfrag[2];
    {
        int qr = qrow_base + l15;
        long qtok = sstart + off + (long)r * qr;
        const float* qp = Qg + qtok * 768 + head * 64 + lhi * 8;
#pragma unroll
        for (int dc = 0; dc < 2; dc++) {
            f32x4 a = *(const f32x4*)(qp + dc * 32);
            f32x4 b = *(const f32x4*)(qp + dc * 32 + 4);
#pragma unroll
            for (int j = 0; j < 4; j++) {
                qfrag[dc][j]     = (__bf16)(a[j] * qscale);
                qfrag[dc][4 + j] = (__bf16)(b[j] * qscale);
            }
        }
    }

    f32x4 acc[4] = {};
    float m_run[4] = {-INFINITY, -INFINITY, -INFINITY, -INFINITY};
    float l_run[4] = {0.f, 0.f, 0.f, 0.f};

    const int tokK = tid >> 2, q4 = tid & 3;       // K staging: (token, d-quarter)
    const int tokP = tid >> 3, d8 = (tid & 7) * 8; // V staging: (token-pair, 8 d)

    for (int kt = kt_begin; kt < kt_end; kt++) {
        __syncthreads();                       // prior tile's readers done
        // ---- stage K (row-major) and V (transposed), bf16 swizzled ----
        {
            long ktok = sstart + off + (long)r * (kt * 64 + tokK);
            const float* kp = Kg + ktok * 768 + head * 64 + q4 * 16;
            f32x4 k0 = *(const f32x4*)(kp);
            f32x4 k1 = *(const f32x4*)(kp + 4);
            f32x4 k2 = *(const f32x4*)(kp + 8);
            f32x4 k3 = *(const f32x4*)(kp + 12);
            bf16x8 w0, w1;
#pragma unroll
            for (int j = 0; j < 4; j++) {
                w0[j] = (__bf16)k0[j]; w0[4 + j] = (__bf16)k1[j];
                w1[j] = (__bf16)k2[j]; w1[4 + j] = (__bf16)k3[j];
            }
            int kbase = tokK * 128 + q4 * 32;
            *(bf16x8*)((char*)K_lds + ((kbase)      ^ KSWZ(tokK))) = w0;
            *(bf16x8*)((char*)K_lds + ((kbase + 16) ^ KSWZ(tokK))) = w1;

            long vt0 = sstart + off + (long)r * (kt * 64 + 2 * tokP);
            const float* vp0 = Vg + vt0 * 768 + head * 64 + d8;
            const float* vp1 = vp0 + (long)r * 768;
            f32x4 a0 = *(const f32x4*)(vp0);
            f32x4 a1 = *(const f32x4*)(vp0 + 4);
            f32x4 b0 = *(const f32x4*)(vp1);
            f32x4 b1 = *(const f32x4*)(vp1 + 4);
#pragma unroll
            for (int j = 0; j < 4; j++) {
                int d = d8 + j;
                bf16x2 w; w[0] = (__bf16)a0[j]; w[1] = (__bf16)b0[j];
                *(bf16x2*)((char*)Vt_lds + ((d * 128 + tokP * 4) ^ VSWZ(d))) = w;
                int d2 = d8 + 4 + j;
                bf16x2 w2; w2[0] = (__bf16)a1[j]; w2[1] = (__bf16)b1[j];
                *(bf16x2*)((char*)Vt_lds + ((d2 * 128 + tokP * 4) ^ VSWZ(d2))) = w2;
            }
        }
        __syncthreads();                       // tile staged

        // ---- S = Q K^T ----
        f32x4 s[4];
#pragma unroll
        for (int nt = 0; nt < 4; nt++) {
            f32x4 cc = {};
#pragma unroll
            for (int dc = 0; dc < 2; dc++) {
                int krow = nt * 16 + l15;
                const bf16x8 kf = *(const bf16x8*)((char*)K_lds +
                    ((krow * 128 + dc * 64 + lhi * 16) ^ KSWZ(krow)));
                cc = __builtin_amdgcn_mfma_f32_16x16x32_bf16(qfrag[dc], kf, cc, 0, 0, 0);
            }
            s[nt] = cc;
        }
        // ---- causal mask (diagonal tile only) ----
        if (causal && kt == qt) {
#pragma unroll
            for (int nt = 0; nt < 4; nt++) {
                int kc = kt * 64 + nt * 16 + l15;
#pragma unroll
                for (int reg = 0; reg < 4; reg++) {
                    int qr = qrow_base + lhi * 4 + reg;
                    if (kc > qr) s[nt][reg] = -INFINITY;
                }
            }
        }
        // ---- online softmax (16-lane row groups) ----
        float sc_reg[4];
#pragma unroll
        for (int reg = 0; reg < 4; reg++) {
            float mt = fmaxf(fmaxf(s[0][reg], s[1][reg]), fmaxf(s[2][reg], s[3][reg]));
#pragma unroll
            for (int x = 1; x < 16; x <<= 1) mt = fmaxf(mt, __shfl_xor(mt, x));
            float mn = fmaxf(m_run[reg], mt);
            float sc = exp2f(m_run[reg] - mn);
            float ps = 0.f;
#pragma unroll
            for (int nt = 0; nt < 4; nt++) {
                float p = exp2f(s[nt][reg] - mn);
                s[nt][reg] = p;
                ps += p;
            }
#pragma unroll
            for (int x = 1; x < 16; x <<= 1) ps += __shfl_xor(ps, x);
            l_run[reg] = l_run[reg] * sc + ps;
            m_run[reg] = mn;
            sc_reg[reg] = sc;
        }
#pragma unroll
        for (int dt = 0; dt < 4; dt++)
#pragma unroll
            for (int reg = 0; reg < 4; reg++) acc[dt][reg] *= sc_reg[reg];
        // ---- P -> wave-private LDS bridge ----
        char* pl = (char*)P_lds[wave];
#pragma unroll
        for (int reg = 0; reg < 4; reg++) {
            int row = lhi * 4 + reg;
            int rs = (row & 7) << 4;
#pragma unroll
            for (int nt = 0; nt < 4; nt++) {
                int colb = (nt * 16 + l15) * 2;
                *(__bf16*)(pl + ((row * 128 + colb) ^ rs)) = (__bf16)s[nt][reg];
            }
        }
        // ---- O += P V ----
#pragma unroll
        for (int kc = 0; kc < 2; kc++) {
            const bf16x8 pf = *(const bf16x8*)(pl +
                ((l15 * 128 + kc * 64 + lhi * 16) ^ ((l15 & 7) << 4)));
#pragma unroll
            for (int dt = 0; dt < 4; dt++) {
                int drow = dt * 16 + l15;
                const bf16x8 vf = *(const bf16x8*)((char*)Vt_lds +
                    ((drow * 128 + kc * 64 + lhi * 16) ^ VSWZ(drow)));
                acc[dt] = __builtin_amdgcn_mfma_f32_16x16x32_bf16(pf, vf, acc[dt], 0, 0, 0);
            }
        }
    }

    if (direct) {
        // ---- normalize + scatter to output ----
#pragma unroll
        for (int reg = 0; reg < 4; reg++) {
            float inv = 1.0f / l_run[reg];
            int qr = qrow_base + lhi * 4 + reg;
            long tok = sstart + off + (long)r * qr;
            float* op = Og + tok * 768 + head * 64 + l15;
#pragma unroll
            for (int dt = 0; dt < 4; dt++) op[dt * 16] = acc[dt][reg] * inv;
        }
    } else {
        // ---- write unnormalized partial to ws ----
        float* slotp = ws + (size_t)(inst * 72 + (u - 8)) * 4224;
#pragma unroll
        for (int reg = 0; reg < 4; reg++) {
            int row = wave * 16 + lhi * 4 + reg;
            float* op = slotp + row * 64 + l15;
#pragma unroll
            for (int dt = 0; dt < 4; dt++) op[dt * 16] = acc[dt][reg];
            if (l15 == 0) {
                slotp[4096 + row] = m_run[reg];
                slotp[4160 + row] = l_run[reg];
            }
        }
    }
}

__global__ __launch_bounds__(256)
void dilattn_merge(const float* __restrict__ ws, float* __restrict__ Og,
                   const int* __restrict__ causal_p)
{
    if (!*causal_p) return;                    // non-causal handled directly
    const int bid  = blockIdx.x;
    const int inst = bid / 24;
    const int qt   = 8 + bid % 24;
    int head, sstart, r, off;
    inst_decode(inst, head, sstart, r, off);

    const int nc = (qt + 8) >> 3;              // ceil((qt+1)/8): 2..4
    const int b  = (qt < 16) ? (qt - 8) * 2
                 : (qt < 24) ? 16 + (qt - 16) * 3
                 : 40 + (qt - 24) * 4;
    const float* base = ws + (size_t)(inst * 72 + b) * 4224;

    const int tid = threadIdx.x;
    const int row = tid >> 2;
    const int c4  = (tid & 3) * 16;

    float mv[4], lv[4];
    float m = -INFINITY;
#pragma unroll
    for (int c = 0; c < 4; c++) {
        if (c < nc) {
            mv[c] = base[c * 4224 + 4096 + row];
            lv[c] = base[c * 4224 + 4160 + row];
            m = fmaxf(m, mv[c]);
        }
    }
    float w[4];
    float L = 0.f;
#pragma unroll
    for (int c = 0; c < 4; c++) {
        if (c < nc) {
            w[c] = exp2f(mv[c] - m);
            L += w[c] * lv[c];
        }
    }
    const float invL = 1.0f / L;

    f32x4 o[4] = {};
#pragma unroll
    for (int c = 0; c < 4; c++) {
        if (c < nc) {
            const float* op = base + c * 4224 + row * 64 + c4;
#pragma unroll
            for (int j = 0; j < 4; j++) {
                f32x4 t = *(const f32x4*)(op + j * 4);
#pragma unroll
                for (int e = 0; e < 4; e++) o[j][e] += w[c] * t[e];
            }
        }
    }

    long tok = sstart + off + (long)r * (qt * 64 + row);
    float* og = Og + tok * 768 + head * 64 + c4;
#pragma unroll
    for (int j = 0; j < 4; j++) {
        f32x4 t;
#pragma unroll
        for (int e = 0; e < 4; e++) t[e] = o[j][e] * invL;
        *(f32x4*)(og + j * 4) = t;
    }
}

extern "C" void kernel_launch(void* const* d_in, const int* in_sizes, int n_in,
                              void* d_out, int out_size, void* d_ws, size_t ws_size,
                              hipStream_t stream)
{
    const float* q = (const float*)d_in[0];
    const float* k = (const float*)d_in[1];
    const float* v = (const float*)d_in[2];
    const int* causal = (const int*)d_in[3];
    float* out = (float*)d_out;
    float* ws  = (float*)d_ws;

    hipMemsetAsync(d_out, 0, (size_t)out_size * sizeof(float), stream);

    dilattn_partial<<<dim3(28 * 80), dim3(256), 0, stream>>>(q, k, v, out, ws, causal);
    dilattn_merge<<<dim3(28 * 24), dim3(256), 0, stream>>>(ws, out, causal);
}

// Round 5
// 78.958 us; speedup vs baseline: 3.3348x; 1.2671x over previous
//
#include <hip/hip_runtime.h>

typedef __attribute__((ext_vector_type(8))) __bf16 bf16x8;
typedef __attribute__((ext_vector_type(4))) __bf16 bf16x4;
typedef __attribute__((ext_vector_type(2))) __bf16 bf16x2;
typedef __attribute__((ext_vector_type(4))) float f32x4;

#define LOG2E 1.44269504088896f
#define KSWZ(t) (((t) & 7) << 4)
#define VSWZ(d) ((((d) & 7) ^ (((d) >> 3) & 7)) << 4)

// 28 instances of dilated causal attention, each L=2048, d=64.
// q/k/v: (1, 8192, 12, 64) fp32 -> elem = tok*768 + head*64 + d.
// Flash-decode: each (inst, qt) -> ceil((qt+1)/8) chunks of <=8 KV tiles;
// 80 units/inst, 2240 blocks, XCD-chunked (bid%8 -> contiguous unit range).
// Swapped QK^T: S' = K·Q^T so each lane owns one q column -> in-register
// softmax (2 shfl_xor per reduce). Double-buffered LDS, 1 barrier/tile,
// loads issued before compute (latency hidden under MFMA/softmax).
// ws slot: 4224 floats = O[64][64] + m[64] + l[64]; slot = inst*72 + (u-8).

__device__ __forceinline__ void inst_decode(int inst, int& head, int& sstart,
                                            int& r, int& off)
{
    if (inst < 16)      { head = inst & 3;          sstart = (inst >> 2) * 2048; r = 1; off = 0; }
    else if (inst < 24) { int j = inst - 16; head = 4 + (j & 3); sstart = (j >> 2) * 4096; r = 2; off = 1; }
    else                { head = 8 + (inst - 24);   sstart = 0;                  r = 4; off = 2; }
}

__global__ __launch_bounds__(256)
void dilattn_partial(const float* __restrict__ Qg, const float* __restrict__ Kg,
                     const float* __restrict__ Vg, float* __restrict__ Og,
                     float* __restrict__ ws, const int* __restrict__ causal_p)
{
    const int bid  = blockIdx.x;
    const int unit = (bid & 7) * 280 + (bid >> 3);   // XCD-contiguous units
    const int inst = unit / 80;
    const int u    = 79 - (unit % 80);               // heavy chunks first
    int qt, c;
    if (u < 8) { qt = u; c = 0; }
    else {
        int v = u - 8;
        if (v < 16)      { qt = 8  + (v >> 1); c = v & 1; }
        else if (v < 40) { int t = v - 16; int q3 = t / 3; qt = 16 + q3; c = t - 3 * q3; }
        else             { int t = v - 40; qt = 24 + (t >> 2); c = t & 3; }
    }
    int head, sstart, r, off;
    inst_decode(inst, head, sstart, r, off);

    const int causal = *causal_p;
    int kt_begin, kt_end;
    bool direct;
    if (causal) {
        int nkt = qt + 1;
        kt_begin = c * 8;
        kt_end   = (kt_begin + 8 < nkt) ? kt_begin + 8 : nkt;
        direct   = (qt < 8);
    } else {
        if (c) return;
        kt_begin = 0; kt_end = 32; direct = true;
    }

    const int tid  = threadIdx.x;
    const int lane = tid & 63;
    const int wave = tid >> 6;                 // 0..3
    const int l15  = lane & 15;
    const int lhi  = lane >> 4;

    __shared__ char KV[2][16384];              // per buf: K 8K | V^T 8K
    __shared__ __bf16 P_lds[4][16 * 64];       // per-wave P bridge (swizzled)

    // ---- Q fragments (scale * log2e folded in); also serves as MFMA B ----
    const int qrow_base = qt * 64 + wave * 16;
    const float qscale = 0.125f * LOG2E;
    bf16x8 qfrag[2];
    {
        int qr = qrow_base + l15;
        long qtok = sstart + off + (long)r * qr;
        const float* qp = Qg + qtok * 768 + head * 64 + lhi * 8;
#pragma unroll
        for (int dc = 0; dc < 2; dc++) {
            f32x4 a = *(const f32x4*)(qp + dc * 32);
            f32x4 b = *(const f32x4*)(qp + dc * 32 + 4);
#pragma unroll
            for (int j = 0; j < 4; j++) {
                qfrag[dc][j]     = (__bf16)(a[j] * qscale);
                qfrag[dc][4 + j] = (__bf16)(b[j] * qscale);
            }
        }
    }

    f32x4 acc[4] = {};                          // O: row q=lhi*4+reg, col d=dt*16+l15
    float m_run = -INFINITY;                    // per-lane: q = l15
    float l_run = 0.f;

    const int tokK = tid >> 2, q4 = tid & 3;        // K staging: (token, d-quarter)
    const int tokP = tid >> 3, d8 = (tid & 7) * 8;  // V staging: (token-pair, 8 d)

    // staging registers (next tile in flight)
    f32x4 rk0, rk1, rk2, rk3, rv0, rv1, rv2, rv3;

#define LOAD_TILE(KT) do {                                                     \
        long tb = sstart + off + (long)r * ((KT) * 64);                        \
        const float* kp_ = Kg + (tb + (long)r * tokK) * 768 + head * 64 + q4 * 16; \
        rk0 = *(const f32x4*)(kp_);      rk1 = *(const f32x4*)(kp_ + 4);       \
        rk2 = *(const f32x4*)(kp_ + 8);  rk3 = *(const f32x4*)(kp_ + 12);      \
        const float* vp0_ = Vg + (tb + (long)r * 2 * tokP) * 768 + head * 64 + d8; \
        const float* vp1_ = vp0_ + (long)r * 768;                              \
        rv0 = *(const f32x4*)(vp0_);     rv1 = *(const f32x4*)(vp0_ + 4);      \
        rv2 = *(const f32x4*)(vp1_);     rv3 = *(const f32x4*)(vp1_ + 4);      \
    } while (0)

#define STORE_TILE(BUFI) do {                                                  \
        char* Kb_ = KV[(BUFI)];                                                \
        char* Vb_ = KV[(BUFI)] + 8192;                                         \
        bf16x8 w0_, w1_;                                                       \
        _Pragma("unroll")                                                      \
        for (int j = 0; j < 4; j++) {                                          \
            w0_[j] = (__bf16)rk0[j]; w0_[4 + j] = (__bf16)rk1[j];              \
            w1_[j] = (__bf16)rk2[j]; w1_[4 + j] = (__bf16)rk3[j];              \
        }                                                                      \
        int kb_ = tokK * 128 + q4 * 32;                                        \
        *(bf16x8*)(Kb_ + ((kb_)      ^ KSWZ(tokK))) = w0_;                     \
        *(bf16x8*)(Kb_ + ((kb_ + 16) ^ KSWZ(tokK))) = w1_;                     \
        _Pragma("unroll")                                                      \
        for (int j = 0; j < 4; j++) {                                          \
            int d_ = d8 + j;                                                   \
            bf16x2 wa_; wa_[0] = (__bf16)rv0[j]; wa_[1] = (__bf16)rv2[j];      \
            *(bf16x2*)(Vb_ + ((d_ * 128 + tokP * 4) ^ VSWZ(d_))) = wa_;        \
            int d2_ = d8 + 4 + j;                                              \
            bf16x2 wb_; wb_[0] = (__bf16)rv1[j]; wb_[1] = (__bf16)rv3[j];      \
            *(bf16x2*)(Vb_ + ((d2_ * 128 + tokP * 4) ^ VSWZ(d2_))) = wb_;      \
        }                                                                      \
    } while (0)

    // ---- prologue: stage first tile ----
    LOAD_TILE(kt_begin);
    STORE_TILE(0);
    __syncthreads();

    int bufi = 0;
    for (int kt = kt_begin; kt < kt_end; kt++) {
        const bool pf = (kt + 1 < kt_end);
        if (pf) LOAD_TILE(kt + 1);             // issue early; lands under compute

        char* Kb = KV[bufi];
        char* Vb = KV[bufi] + 8192;

        // ---- S' = K Q^T : lane owns q = l15; regs (nt,reg) = k values ----
        f32x4 s[4];
#pragma unroll
        for (int nt = 0; nt < 4; nt++) {
            f32x4 cc = {};
#pragma unroll
            for (int dc = 0; dc < 2; dc++) {
                int krow = nt * 16 + l15;
                const bf16x8 kf = *(const bf16x8*)(Kb +
                    ((krow * 128 + dc * 64 + lhi * 16) ^ KSWZ(krow)));
                cc = __builtin_amdgcn_mfma_f32_16x16x32_bf16(kf, qfrag[dc], cc, 0, 0, 0);
            }
            s[nt] = cc;
        }
        // ---- causal mask (diagonal tile only): k > q ----
        if (causal && kt == qt) {
#pragma unroll
            for (int nt = 0; nt < 4; nt++)
#pragma unroll
                for (int reg = 0; reg < 4; reg++)
                    if (nt * 16 + lhi * 4 + reg > wave * 16 + l15)
                        s[nt][reg] = -INFINITY;
        }

        // ---- in-register online softmax (per-lane q = l15) ----
        float mt = fmaxf(fmaxf(s[0][0], s[0][1]), fmaxf(s[0][2], s[0][3]));
#pragma unroll
        for (int nt = 1; nt < 4; nt++)
            mt = fmaxf(mt, fmaxf(fmaxf(s[nt][0], s[nt][1]), fmaxf(s[nt][2], s[nt][3])));
        mt = fmaxf(mt, __shfl_xor(mt, 16));
        mt = fmaxf(mt, __shfl_xor(mt, 32));
        float mn = fmaxf(m_run, mt);
        float sc = exp2f(m_run - mn);
        float ps = 0.f;
#pragma unroll
        for (int nt = 0; nt < 4; nt++)
#pragma unroll
            for (int reg = 0; reg < 4; reg++) {
                float p = exp2f(s[nt][reg] - mn);
                s[nt][reg] = p;
                ps += p;
            }
        ps += __shfl_xor(ps, 16);
        ps += __shfl_xor(ps, 32);
        l_run = l_run * sc + ps;
        m_run = mn;

        // ---- rescale O (sc is per-q; fetch for q = lhi*4+reg) ----
        float scr[4];
#pragma unroll
        for (int reg = 0; reg < 4; reg++) scr[reg] = __shfl(sc, lhi * 4 + reg);
#pragma unroll
        for (int dt = 0; dt < 4; dt++)
#pragma unroll
            for (int reg = 0; reg < 4; reg++) acc[dt][reg] *= scr[reg];

        // ---- P -> wave-private LDS bridge: 4 consecutive k per write ----
        char* pl = (char*)P_lds[wave];
        const int rs = (l15 & 7) << 4;
#pragma unroll
        for (int nt = 0; nt < 4; nt++) {
            bf16x4 pw;
#pragma unroll
            for (int reg = 0; reg < 4; reg++) pw[reg] = (__bf16)s[nt][reg];
            *(bf16x4*)(pl + ((l15 * 128 + (nt * 16 + lhi * 4) * 2) ^ rs)) = pw;
        }

        // ---- O += P V ----
#pragma unroll
        for (int kc = 0; kc < 2; kc++) {
            const bf16x8 pfg = *(const bf16x8*)(pl +
                ((l15 * 128 + kc * 64 + lhi * 16) ^ rs));
#pragma unroll
            for (int dt = 0; dt < 4; dt++) {
                int drow = dt * 16 + l15;
                const bf16x8 vf = *(const bf16x8*)(Vb +
                    ((drow * 128 + kc * 64 + lhi * 16) ^ VSWZ(drow)));
                acc[dt] = __builtin_amdgcn_mfma_f32_16x16x32_bf16(pfg, vf, acc[dt], 0, 0, 0);
            }
        }

        if (pf) STORE_TILE(bufi ^ 1);          // publish next tile
        __syncthreads();
        bufi ^= 1;
    }

    if (direct) {
        // ---- normalize + scatter ----
        float lq[4];
#pragma unroll
        for (int reg = 0; reg < 4; reg++) lq[reg] = __shfl(l_run, lhi * 4 + reg);
#pragma unroll
        for (int reg = 0; reg < 4; reg++) {
            float inv = 1.0f / lq[reg];
            int qr = qrow_base + lhi * 4 + reg;
            long tok = sstart + off + (long)r * qr;
            float* op = Og + tok * 768 + head * 64 + l15;
#pragma unroll
            for (int dt = 0; dt < 4; dt++) op[dt * 16] = acc[dt][reg] * inv;
        }
    } else {
        // ---- write unnormalized partial to ws ----
        float* slotp = ws + (size_t)(inst * 72 + (u - 8)) * 4224;
#pragma unroll
        for (int reg = 0; reg < 4; reg++) {
            int row = wave * 16 + lhi * 4 + reg;
            float* op = slotp + row * 64 + l15;
#pragma unroll
            for (int dt = 0; dt < 4; dt++) op[dt * 16] = acc[dt][reg];
        }
        if (lhi == 0) {                         // lane owns q = l15
            slotp[4096 + wave * 16 + l15] = m_run;
            slotp[4160 + wave * 16 + l15] = l_run;
        }
    }
#undef LOAD_TILE
#undef STORE_TILE
}

__global__ __launch_bounds__(256)
void dilattn_merge(const float* __restrict__ ws, float* __restrict__ Og,
                   const int* __restrict__ causal_p)
{
    if (!*causal_p) return;
    const int bid  = blockIdx.x;
    const int inst = bid / 24;
    const int qt   = 8 + bid % 24;
    int head, sstart, r, off;
    inst_decode(inst, head, sstart, r, off);

    const int nc = (qt + 8) >> 3;              // 2..4 chunks
    const int b  = (qt < 16) ? (qt - 8) * 2
                 : (qt < 24) ? 16 + (qt - 16) * 3
                 : 40 + (qt - 24) * 4;
    const float* base = ws + (size_t)(inst * 72 + b) * 4224;

    const int tid = threadIdx.x;
    const int row = tid >> 2;
    const int c4  = (tid & 3) * 16;

    float mv[4], lv[4];
    float m = -INFINITY;
#pragma unroll
    for (int c = 0; c < 4; c++) {
        if (c < nc) {
            mv[c] = base[c * 4224 + 4096 + row];
            lv[c] = base[c * 4224 + 4160 + row];
            m = fmaxf(m, mv[c]);
        }
    }
    float w[4];
    float L = 0.f;
#pragma unroll
    for (int c = 0; c < 4; c++) {
        if (c < nc) {
            w[c] = exp2f(mv[c] - m);
            L += w[c] * lv[c];
        }
    }
    const float invL = 1.0f / L;

    f32x4 o[4] = {};
#pragma unroll
    for (int c = 0; c < 4; c++) {
        if (c < nc) {
            const float* op = base + c * 4224 + row * 64 + c4;
#pragma unroll
            for (int j = 0; j < 4; j++) {
                f32x4 t = *(const f32x4*)(op + j * 4);
#pragma unroll
                for (int e = 0; e < 4; e++) o[j][e] += w[c] * t[e];
            }
        }
    }

    long tok = sstart + off + (long)r * (qt * 64 + row);
    float* og = Og + tok * 768 + head * 64 + c4;
#pragma unroll
    for (int j = 0; j < 4; j++) {
        f32x4 t;
#pragma unroll
        for (int e = 0; e < 4; e++) t[e] = o[j][e] * invL;
        *(f32x4*)(og + j * 4) = t;
    }
}

extern "C" void kernel_launch(void* const* d_in, const int* in_sizes, int n_in,
                              void* d_out, int out_size, void* d_ws, size_t ws_size,
                              hipStream_t stream)
{
    const float* q = (const float*)d_in[0];
    const float* k = (const float*)d_in[1];
    const float* v = (const float*)d_in[2];
    const int* causal = (const int*)d_in[3];
    float* out = (float*)d_out;
    float* ws  = (float*)d_ws;

    hipMemsetAsync(d_out, 0, (size_t)out_size * sizeof(float), stream);

    dilattn_partial<<<dim3(28 * 80), dim3(256), 0, stream>>>(q, k, v, out, ws, causal);
    dilattn_merge<<<dim3(28 * 24), dim3(256), 0, stream>>>(ws, out, causal);
}

// Round 6
// 75.272 us; speedup vs baseline: 3.4981x; 1.0490x over previous
//
#include <hip/hip_runtime.h>

typedef __attribute__((ext_vector_type(8))) __bf16 bf16x8;
typedef __attribute__((ext_vector_type(4))) __bf16 bf16x4;
typedef __attribute__((ext_vector_type(2))) __bf16 bf16x2;
typedef __attribute__((ext_vector_type(4))) float f32x4;

#define LOG2E 1.44269504088896f
#define KSWZ(t) (((t) & 7) << 4)
#define VSWZ(d) ((((d) & 7) ^ (((d) >> 3) & 7)) << 4)

// 28 instances of dilated causal attention, each L=2048, d=64.
// q/k/v: (1, 8192, 12, 64) fp32 -> elem = tok*768 + head*64 + d.
// QBLK=128 (8 waves x 16 q-rows), KV tile 64, chunks of <=8 KV tiles:
// 40 units/inst -> 1120 blocks, XCD-chunked, heavy-first.
// Staging is wave-specialized: waves 0-3 stage K, waves 4-7 stage V^T.
// Swapped QK^T -> in-register softmax; T13 defer-max (THR=8, log2 domain).
// ws slot: 8448 floats = O[128][64] + m[128] + l[128]; slot = inst*36+(u-4).

__device__ __forceinline__ void inst_decode(int inst, int& head, int& sstart,
                                            int& r, int& off)
{
    if (inst < 16)      { head = inst & 3;          sstart = (inst >> 2) * 2048; r = 1; off = 0; }
    else if (inst < 24) { int j = inst - 16; head = 4 + (j & 3); sstart = (j >> 2) * 4096; r = 2; off = 1; }
    else                { head = 8 + (inst - 24);   sstart = 0;                  r = 4; off = 2; }
}

__global__ __launch_bounds__(512)
void dilattn_partial(const float* __restrict__ Qg, const float* __restrict__ Kg,
                     const float* __restrict__ Vg, float* __restrict__ Og,
                     float* __restrict__ ws, const int* __restrict__ causal_p)
{
    const int bid  = blockIdx.x;
    const int unit = (bid & 7) * 140 + (bid >> 3);   // XCD-contiguous units
    const int inst = unit / 40;
    const int u    = 39 - (unit % 40);               // heavy chunks first
    int qt, c;
    if (u < 4) { qt = u; c = 0; }
    else {
        int v = u - 4;
        if (v < 8)       { qt = 4 + (v >> 1); c = v & 1; }
        else if (v < 20) { int t = v - 8; int q3 = t / 3; qt = 8 + q3; c = t - 3 * q3; }
        else             { int t = v - 20; qt = 12 + (t >> 2); c = t & 3; }
    }
    int head, sstart, r, off;
    inst_decode(inst, head, sstart, r, off);

    const int causal = *causal_p;
    int kt_begin, kt_end;
    bool direct;
    if (causal) {
        int nkt = 2 * qt + 2;
        kt_begin = c * 8;
        kt_end   = (kt_begin + 8 < nkt) ? kt_begin + 8 : nkt;
        direct   = (qt < 4);
    } else {
        if (c) return;
        kt_begin = 0; kt_end = 32; direct = true;
    }

    const int tid  = threadIdx.x;
    const int lane = tid & 63;
    const int wave = tid >> 6;                 // 0..7
    const int l15  = lane & 15;
    const int lhi  = lane >> 4;

    __shared__ char KV[2][16384];              // per buf: K 8K | V^T 8K
    __shared__ __bf16 P_lds[8][16 * 64];       // per-wave P bridge (swizzled)

    // ---- Q fragments (scale * log2e folded in); serves as MFMA B ----
    const int qrow_base = qt * 128 + wave * 16;
    const float qscale = 0.125f * LOG2E;
    bf16x8 qfrag[2];
    {
        int qr = qrow_base + l15;
        long qtok = sstart + off + (long)r * qr;
        const float* qp = Qg + qtok * 768 + head * 64 + lhi * 8;
#pragma unroll
        for (int dc = 0; dc < 2; dc++) {
            f32x4 a = *(const f32x4*)(qp + dc * 32);
            f32x4 b = *(const f32x4*)(qp + dc * 32 + 4);
#pragma unroll
            for (int j = 0; j < 4; j++) {
                qfrag[dc][j]     = (__bf16)(a[j] * qscale);
                qfrag[dc][4 + j] = (__bf16)(b[j] * qscale);
            }
        }
    }

    f32x4 acc[4] = {};                          // O: row q=lhi*4+reg, col d=dt*16+l15
    float m_run = -INFINITY;                    // per-lane: q = l15
    float l_run = 0.f;

    // ---- wave-specialized staging roles ----
    const bool isK = (wave < 4);
    const int t2   = tid & 255;
    const int tokK = t2 >> 2, q4 = t2 & 3;          // K: (token, d-quarter)
    const int tokP = t2 >> 3, d8 = (t2 & 7) * 8;    // V: (token-pair, 8 d)

    f32x4 r0, r1, r2, r3;                       // staging regs (next tile)

#define LOAD_TILE(KT) do {                                                     \
        long tb = sstart + off + (long)r * ((KT) * 64);                        \
        if (isK) {                                                             \
            const float* p_ = Kg + (tb + (long)r * tokK) * 768 + head * 64 + q4 * 16; \
            r0 = *(const f32x4*)(p_);      r1 = *(const f32x4*)(p_ + 4);       \
            r2 = *(const f32x4*)(p_ + 8);  r3 = *(const f32x4*)(p_ + 12);      \
        } else {                                                               \
            const float* p0_ = Vg + (tb + (long)r * 2 * tokP) * 768 + head * 64 + d8; \
            const float* p1_ = p0_ + (long)r * 768;                            \
            r0 = *(const f32x4*)(p0_);     r1 = *(const f32x4*)(p0_ + 4);      \
            r2 = *(const f32x4*)(p1_);     r3 = *(const f32x4*)(p1_ + 4);      \
        }                                                                      \
    } while (0)

#define STORE_TILE(BUFI) do {                                                  \
        if (isK) {                                                             \
            char* Kb_ = KV[(BUFI)];                                            \
            bf16x8 w0_, w1_;                                                   \
            _Pragma("unroll")                                                  \
            for (int j = 0; j < 4; j++) {                                      \
                w0_[j] = (__bf16)r0[j]; w0_[4 + j] = (__bf16)r1[j];            \
                w1_[j] = (__bf16)r2[j]; w1_[4 + j] = (__bf16)r3[j];            \
            }                                                                  \
            int kb_ = tokK * 128 + q4 * 32;                                    \
            *(bf16x8*)(Kb_ + ((kb_)      ^ KSWZ(tokK))) = w0_;                 \
            *(bf16x8*)(Kb_ + ((kb_ + 16) ^ KSWZ(tokK))) = w1_;                 \
        } else {                                                               \
            char* Vb_ = KV[(BUFI)] + 8192;                                     \
            _Pragma("unroll")                                                  \
            for (int j = 0; j < 4; j++) {                                      \
                int d_ = d8 + j;                                               \
                bf16x2 wa_; wa_[0] = (__bf16)r0[j]; wa_[1] = (__bf16)r2[j];    \
                *(bf16x2*)(Vb_ + ((d_ * 128 + tokP * 4) ^ VSWZ(d_))) = wa_;    \
                int d2_ = d8 + 4 + j;                                          \
                bf16x2 wb_; wb_[0] = (__bf16)r1[j]; wb_[1] = (__bf16)r3[j];    \
                *(bf16x2*)(Vb_ + ((d2_ * 128 + tokP * 4) ^ VSWZ(d2_))) = wb_;  \
            }                                                                  \
        }                                                                      \
    } while (0)

    // ---- prologue: stage first tile ----
    LOAD_TILE(kt_begin);
    STORE_TILE(0);
    __syncthreads();

    int bufi = 0;
    for (int kt = kt_begin; kt < kt_end; kt++) {
        const bool pf = (kt + 1 < kt_end);
        if (pf) LOAD_TILE(kt + 1);             // issue early; lands under compute

        char* Kb = KV[bufi];
        char* Vb = KV[bufi] + 8192;

        // ---- S' = K Q^T : lane owns q = l15; regs (nt,reg) = k values ----
        f32x4 s[4];
        __builtin_amdgcn_s_setprio(1);
#pragma unroll
        for (int nt = 0; nt < 4; nt++) {
            f32x4 cc = {};
#pragma unroll
            for (int dc = 0; dc < 2; dc++) {
                int krow = nt * 16 + l15;
                const bf16x8 kf = *(const bf16x8*)(Kb +
                    ((krow * 128 + dc * 64 + lhi * 16) ^ KSWZ(krow)));
                cc = __builtin_amdgcn_mfma_f32_16x16x32_bf16(kf, qfrag[dc], cc, 0, 0, 0);
            }
            s[nt] = cc;
        }
        __builtin_amdgcn_s_setprio(0);

        // ---- causal mask: tiles kt = 2qt, 2qt+1 overlap the diagonal ----
        if (causal && (kt >> 1) == qt) {
            const int kofs = kt * 64 - qt * 128 - wave * 16;  // k_local - q base
#pragma unroll
            for (int nt = 0; nt < 4; nt++)
#pragma unroll
                for (int reg = 0; reg < 4; reg++)
                    if (kofs + nt * 16 + lhi * 4 + reg > l15)
                        s[nt][reg] = -INFINITY;
        }

        // ---- in-register online softmax with defer-max (THR=8, log2) ----
        float mt = fmaxf(fmaxf(s[0][0], s[0][1]), fmaxf(s[0][2], s[0][3]));
#pragma unroll
        for (int nt = 1; nt < 4; nt++)
            mt = fmaxf(mt, fmaxf(fmaxf(s[nt][0], s[nt][1]), fmaxf(s[nt][2], s[nt][3])));
        mt = fmaxf(mt, __shfl_xor(mt, 16));
        mt = fmaxf(mt, __shfl_xor(mt, 32));
        if (!__all(mt - m_run <= 8.0f)) {
            float mn = fmaxf(m_run, mt);
            float sc = exp2f(m_run - mn);
            l_run *= sc;
            float scr[4];
#pragma unroll
            for (int reg = 0; reg < 4; reg++) scr[reg] = __shfl(sc, lhi * 4 + reg);
#pragma unroll
            for (int dt = 0; dt < 4; dt++)
#pragma unroll
                for (int reg = 0; reg < 4; reg++) acc[dt][reg] *= scr[reg];
            m_run = mn;
        }
        float ps = 0.f;
#pragma unroll
        for (int nt = 0; nt < 4; nt++)
#pragma unroll
            for (int reg = 0; reg < 4; reg++) {
                float p = exp2f(s[nt][reg] - m_run);
                s[nt][reg] = p;
                ps += p;
            }
        ps += __shfl_xor(ps, 16);
        ps += __shfl_xor(ps, 32);
        l_run += ps;

        // ---- P -> wave-private LDS bridge: 4 consecutive k per write ----
        char* pl = (char*)P_lds[wave];
        const int rs = (l15 & 7) << 4;
#pragma unroll
        for (int nt = 0; nt < 4; nt++) {
            bf16x4 pw;
#pragma unroll
            for (int reg = 0; reg < 4; reg++) pw[reg] = (__bf16)s[nt][reg];
            *(bf16x4*)(pl + ((l15 * 128 + (nt * 16 + lhi * 4) * 2) ^ rs)) = pw;
        }

        // ---- O += P V ----
        __builtin_amdgcn_s_setprio(1);
#pragma unroll
        for (int kc = 0; kc < 2; kc++) {
            const bf16x8 pfg = *(const bf16x8*)(pl +
                ((l15 * 128 + kc * 64 + lhi * 16) ^ rs));
#pragma unroll
            for (int dt = 0; dt < 4; dt++) {
                int drow = dt * 16 + l15;
                const bf16x8 vf = *(const bf16x8*)(Vb +
                    ((drow * 128 + kc * 64 + lhi * 16) ^ VSWZ(drow)));
                acc[dt] = __builtin_amdgcn_mfma_f32_16x16x32_bf16(pfg, vf, acc[dt], 0, 0, 0);
            }
        }
        __builtin_amdgcn_s_setprio(0);

        if (pf) STORE_TILE(bufi ^ 1);          // publish next tile
        __syncthreads();
        bufi ^= 1;
    }

    if (direct) {
        // ---- normalize + scatter ----
        float lq[4];
#pragma unroll
        for (int reg = 0; reg < 4; reg++) lq[reg] = __shfl(l_run, lhi * 4 + reg);
#pragma unroll
        for (int reg = 0; reg < 4; reg++) {
            float inv = 1.0f / lq[reg];
            int qr = qrow_base + lhi * 4 + reg;
            long tok = sstart + off + (long)r * qr;
            float* op = Og + tok * 768 + head * 64 + l15;
#pragma unroll
            for (int dt = 0; dt < 4; dt++) op[dt * 16] = acc[dt][reg] * inv;
        }
    } else {
        // ---- write unnormalized partial to ws ----
        float* slotp = ws + (size_t)(inst * 36 + (u - 4)) * 8448;
#pragma unroll
        for (int reg = 0; reg < 4; reg++) {
            int row = wave * 16 + lhi * 4 + reg;
            float* op = slotp + row * 64 + l15;
#pragma unroll
            for (int dt = 0; dt < 4; dt++) op[dt * 16] = acc[dt][reg];
        }
        if (lhi == 0) {                         // lane owns q = l15
            slotp[8192 + wave * 16 + l15] = m_run;
            slotp[8320 + wave * 16 + l15] = l_run;
        }
    }
#undef LOAD_TILE
#undef STORE_TILE
}

__global__ __launch_bounds__(256)
void dilattn_merge(const float* __restrict__ ws, float* __restrict__ Og,
                   const int* __restrict__ causal_p)
{
    if (!*causal_p) return;
    const int bid  = blockIdx.x;
    const int inst = bid / 12;
    const int qt   = 4 + bid % 12;
    int head, sstart, r, off;
    inst_decode(inst, head, sstart, r, off);

    const int nc = (2 * qt + 9) >> 3;          // ceil((2qt+2)/8): 2..4
    const int b  = (qt < 8)  ? (qt - 4) * 2
                 : (qt < 12) ? 8 + (qt - 8) * 3
                 :             20 + (qt - 12) * 4;
    const float* base = ws + (size_t)(inst * 36 + b) * 8448;

    const int tid = threadIdx.x;
    const int row = tid >> 1;                  // 0..127
    const int c32 = (tid & 1) * 32;

    float mv[4], lv[4];
    float m = -INFINITY;
#pragma unroll
    for (int c = 0; c < 4; c++) {
        if (c < nc) {
            mv[c] = base[c * 8448 + 8192 + row];
            lv[c] = base[c * 8448 + 8320 + row];
            m = fmaxf(m, mv[c]);
        }
    }
    float w[4];
    float L = 0.f;
#pragma unroll
    for (int c = 0; c < 4; c++) {
        if (c < nc) {
            w[c] = exp2f(mv[c] - m);
            L += w[c] * lv[c];
        }
    }
    const float invL = 1.0f / L;

    f32x4 o[8] = {};
#pragma unroll
    for (int c = 0; c < 4; c++) {
        if (c < nc) {
            const float* op = base + c * 8448 + row * 64 + c32;
#pragma unroll
            for (int j = 0; j < 8; j++) {
                f32x4 t = *(const f32x4*)(op + j * 4);
#pragma unroll
                for (int e = 0; e < 4; e++) o[j][e] += w[c] * t[e];
            }
        }
    }

    long tok = sstart + off + (long)r * (qt * 128 + row);
    float* og = Og + tok * 768 + head * 64 + c32;
#pragma unroll
    for (int j = 0; j < 8; j++) {
        f32x4 t;
#pragma unroll
        for (int e = 0; e < 4; e++) t[e] = o[j][e] * invL;
        *(f32x4*)(og + j * 4) = t;
    }
}

extern "C" void kernel_launch(void* const* d_in, const int* in_sizes, int n_in,
                              void* d_out, int out_size, void* d_ws, size_t ws_size,
                              hipStream_t stream)
{
    const float* q = (const float*)d_in[0];
    const float* k = (const float*)d_in[1];
    const float* v = (const float*)d_in[2];
    const int* causal = (const int*)d_in[3];
    float* out = (float*)d_out;
    float* ws  = (float*)d_ws;

    hipMemsetAsync(d_out, 0, (size_t)out_size * sizeof(float), stream);

    dilattn_partial<<<dim3(28 * 40), dim3(512), 0, stream>>>(q, k, v, out, ws, causal);
    dilattn_merge<<<dim3(28 * 12), dim3(256), 0, stream>>>(ws, out, causal);
}